// Round 1
// 278.095 us; speedup vs baseline: 1.0901x; 1.0901x over previous
//
#include <hip/hip_runtime.h>
#include <hip/hip_bf16.h>

#define D_MODEL 256
#define D_HID   128
#define SEQ     1024
#define NBATCH  32
#define NROWS   (NBATCH * SEQ)    // 32768
#define MASKV   -10000.0f
#define EPSLN   1e-5f

typedef unsigned short u16;
using bf16x8 = __attribute__((ext_vector_type(8))) short;
using f32x4  = __attribute__((ext_vector_type(4))) float;

union U8 { uint4 v; u16 s[8]; };

__device__ __forceinline__ float bf2f(u16 u) {
    unsigned int x = ((unsigned int)u) << 16;
    return __uint_as_float(x);
}
__device__ __forceinline__ u16 f2bf(float f) {
    unsigned int u = __float_as_uint(f);
    u += 0x7fff + ((u >> 16) & 1);   // RNE
    return (u16)(u >> 16);
}
__device__ __forceinline__ void load4(const float* p, float* f) {
    float4 a = *(const float4*)p;
    f[0] = a.x; f[1] = a.y; f[2] = a.z; f[3] = a.w;
}
__device__ __forceinline__ void load4(const u16* p, float* f) {
    ushort4 v = *(const ushort4*)p;
    f[0] = bf2f(v.x); f[1] = bf2f(v.y); f[2] = bf2f(v.z); f[3] = bf2f(v.w);
}
// async global->LDS, 16B per lane; LDS dest = wave-uniform base + lane*16
__device__ __forceinline__ void gload16(const u16* g, u16* l) {
    __builtin_amdgcn_global_load_lds(
        (const __attribute__((address_space(1))) void*)g,
        (__attribute__((address_space(3))) void*)l, 16, 0, 0);
}

// ---------------------------------------------------------------------------
// Weight transposes: fp32 W[K][N] -> bf16 WT[N][K]
// ---------------------------------------------------------------------------
__global__ __launch_bounds__(256) void transpose_weights(
    const float* __restrict__ wqkv, u16* __restrict__ wqkvT,
    const float* __restrict__ wproj, u16* __restrict__ wprojT,
    const float* __restrict__ wfc1, u16* __restrict__ wfc1T,
    const float* __restrict__ wfc2, u16* __restrict__ wfc2T) {
    int tid = blockIdx.x * 256 + threadIdx.x;
    int stride = gridDim.x * 256;
    for (int i = tid; i < 768 * 256; i += stride) {
        int n = i >> 8, k = i & 255;
        wqkvT[i] = f2bf(wqkv[k * 768 + n]);
    }
    for (int i = tid; i < 256 * 256; i += stride) {
        int n = i >> 8, k = i & 255;
        wprojT[i] = f2bf(wproj[k * 256 + n]);
    }
    for (int i = tid; i < 128 * 256; i += stride) {
        int n = i >> 8, k = i & 255;
        wfc1T[i] = f2bf(wfc1[k * 128 + n]);
    }
    for (int i = tid; i < 256 * 128; i += stride) {
        int n = i >> 7, k = i & 127;
        wfc2T[i] = f2bf(wfc2[k * 256 + n]);
    }
}

// ---------------------------------------------------------------------------
// Fused LayerNorm: one wave per row (256 cols, 4/lane), writes bf16 row.
// ---------------------------------------------------------------------------
template <typename TX>
__global__ __launch_bounds__(256) void ln_fused(
    const TX* __restrict__ x, const float* __restrict__ gamma,
    const float* __restrict__ beta, u16* __restrict__ out) {
    int wave = threadIdx.x >> 6, lane = threadIdx.x & 63;
    int row = blockIdx.x * 4 + wave;
    float f[4];
    load4(x + (size_t)row * D_MODEL + lane * 4, f);
    float s  = f[0] + f[1] + f[2] + f[3];
    float sq = f[0] * f[0] + f[1] * f[1] + f[2] * f[2] + f[3] * f[3];
    #pragma unroll
    for (int off = 1; off < 64; off <<= 1) {
        s  += __shfl_xor(s, off);
        sq += __shfl_xor(sq, off);
    }
    float mu   = s * (1.0f / 256.0f);
    float var  = sq * (1.0f / 256.0f) - mu * mu;
    float rstd = rsqrtf(var + EPSLN);
    float g[4], be[4];
    load4(gamma + lane * 4, g);
    load4(beta + lane * 4, be);
    ushort4 o;
    o.x = f2bf((f[0] - mu) * rstd * g[0] + be[0]);
    o.y = f2bf((f[1] - mu) * rstd * g[1] + be[1]);
    o.z = f2bf((f[2] - mu) * rstd * g[2] + be[2]);
    o.w = f2bf((f[3] - mu) * rstd * g[3] + be[3]);
    *(ushort4*)(out + (size_t)row * D_MODEL + lane * 4) = o;
}

// ---------------------------------------------------------------------------
// 128x64 GEMM tile mainloop. 4 waves in 2x2; each wave 64x32 (acc[4][2]).
// ---------------------------------------------------------------------------
#define GEMM_LDS_ELEMS ((128 + 64) * 136)

template <int K>
__device__ __forceinline__ void gemm_tile(
    const u16* __restrict__ A, const u16* __restrict__ BT,
    int m0, int n0, u16* lds, f32x4 acc[4][2]) {
    constexpr int KC = 128, KP = 136;
    u16* ldsA = lds;
    u16* ldsB = lds + 128 * KP;
    const int tid = threadIdx.x;
    const int lane = tid & 63, wave = tid >> 6;
    const int wr = (wave >> 1) * 64, wc = (wave & 1) * 32;
    const int row = lane & 15, quad = lane >> 4;

    for (int ks = 0; ks < K; ks += KC) {
        __syncthreads();
        for (int i = tid; i < 2048; i += 256) {          // A: 128 x 128
            int i8 = i * 8;
            int r = i8 >> 7, c = i8 & 127;
            *(uint4*)(ldsA + r * KP + c) =
                *(const uint4*)(A + (size_t)(m0 + r) * K + ks + c);
        }
        for (int i = tid; i < 1024; i += 256) {          // B: 64 x 128
            int i8 = i * 8;
            int r = i8 >> 7, c = i8 & 127;
            *(uint4*)(ldsB + r * KP + c) =
                *(const uint4*)(BT + (size_t)(n0 + r) * K + ks + c);
        }
        __syncthreads();
        #pragma unroll
        for (int k0 = 0; k0 < KC; k0 += 32) {
            bf16x8 a[4], b[2];
            #pragma unroll
            for (int mi = 0; mi < 4; mi++)
                a[mi] = *(const bf16x8*)(ldsA + (wr + mi * 16 + row) * KP + k0 + quad * 8);
            #pragma unroll
            for (int nj = 0; nj < 2; nj++)
                b[nj] = *(const bf16x8*)(ldsB + (wc + nj * 16 + row) * KP + k0 + quad * 8);
            #pragma unroll
            for (int mi = 0; mi < 4; mi++)
                #pragma unroll
                for (int nj = 0; nj < 2; nj++)
                    acc[mi][nj] = __builtin_amdgcn_mfma_f32_16x16x32_bf16(
                        a[mi], b[nj], acc[mi][nj], 0, 0, 0);
        }
    }
}

#define ZERO_ACC(acc)                                        \
    _Pragma("unroll") for (int i_ = 0; i_ < 4; i_++)         \
    _Pragma("unroll") for (int j_ = 0; j_ < 2; j_++)         \
    _Pragma("unroll") for (int e_ = 0; e_ < 4; e_++) acc[i_][j_][e_] = 0.0f;

#define EPILOG_IDX                                           \
    int lane = threadIdx.x & 63, wave = threadIdx.x >> 6;    \
    int wr = (wave >> 1) * 64, wc = (wave & 1) * 32;         \
    int row = lane & 15, quad = lane >> 4;

// QKV: h @ wqkv + b -> q (pre-scaled 1/16), k, vT[b,256,s]
__global__ __launch_bounds__(256) void gemm_qkv(
    const u16* __restrict__ h, const u16* __restrict__ wqkvT,
    const float* __restrict__ b_qkv,
    u16* __restrict__ q, u16* __restrict__ kk, u16* __restrict__ vT) {
    __shared__ u16 lds[GEMM_LDS_ELEMS];
    f32x4 acc[4][2];
    ZERO_ACC(acc)
    int m0 = blockIdx.x * 128, n0 = blockIdx.y * 64;
    gemm_tile<256>(h, wqkvT, m0, n0, lds, acc);
    EPILOG_IDX
    #pragma unroll
    for (int mi = 0; mi < 4; mi++) {
        #pragma unroll
        for (int nj = 0; nj < 2; nj++) {
            int gn = n0 + wc + nj * 16 + row;
            float bias = b_qkv[gn];
            int gm = m0 + wr + mi * 16 + quad * 4;
            if (gn < 256) {          // q, pre-scaled by 1/sqrt(D)=1/16
                #pragma unroll
                for (int r = 0; r < 4; r++)
                    q[(size_t)(gm + r) * 256 + gn] =
                        f2bf((acc[mi][nj][r] + bias) * 0.0625f);
            } else if (gn < 512) {   // k
                int col = gn - 256;
                #pragma unroll
                for (int r = 0; r < 4; r++)
                    kk[(size_t)(gm + r) * 256 + col] = f2bf(acc[mi][nj][r] + bias);
            } else {                 // v -> vT[b][d][s]
                int d = gn - 512;
                int b = gm >> 10, s = gm & 1023;
                ushort4 pack;
                pack.x = f2bf(acc[mi][nj][0] + bias);
                pack.y = f2bf(acc[mi][nj][1] + bias);
                pack.z = f2bf(acc[mi][nj][2] + bias);
                pack.w = f2bf(acc[mi][nj][3] + bias);
                *(ushort4*)(vT + ((size_t)(b * 256 + d) << 10) + s) = pack;
            }
        }
    }
}

// proj: ao @ wproj + b + residual(x fp32) -> x2 (bf16)
__global__ __launch_bounds__(256) void gemm_proj(
    const u16* __restrict__ ao, const u16* __restrict__ wprojT,
    const float* __restrict__ b_proj, const float* __restrict__ x_in,
    u16* __restrict__ x2) {
    __shared__ u16 lds[GEMM_LDS_ELEMS];
    f32x4 acc[4][2];
    ZERO_ACC(acc)
    int m0 = blockIdx.x * 128, n0 = blockIdx.y * 64;
    gemm_tile<256>(ao, wprojT, m0, n0, lds, acc);
    EPILOG_IDX
    #pragma unroll
    for (int mi = 0; mi < 4; mi++)
        #pragma unroll
        for (int nj = 0; nj < 2; nj++) {
            int gn = n0 + wc + nj * 16 + row;
            float bias = b_proj[gn];
            int gm = m0 + wr + mi * 16 + quad * 4;
            #pragma unroll
            for (int r = 0; r < 4; r++) {
                size_t idx = (size_t)(gm + r) * 256 + gn;
                x2[idx] = f2bf(acc[mi][nj][r] + bias + x_in[idx]);
            }
        }
}

// fc1: h2 @ wfc1 + b, ReLU -> a1
__global__ __launch_bounds__(256) void gemm_fc1(
    const u16* __restrict__ h2, const u16* __restrict__ wfc1T,
    const float* __restrict__ b_fc1, u16* __restrict__ a1) {
    __shared__ u16 lds[GEMM_LDS_ELEMS];
    f32x4 acc[4][2];
    ZERO_ACC(acc)
    int m0 = blockIdx.x * 128, n0 = blockIdx.y * 64;
    gemm_tile<256>(h2, wfc1T, m0, n0, lds, acc);
    EPILOG_IDX
    #pragma unroll
    for (int mi = 0; mi < 4; mi++)
        #pragma unroll
        for (int nj = 0; nj < 2; nj++) {
            int gn = n0 + wc + nj * 16 + row;
            float bias = b_fc1[gn];
            int gm = m0 + wr + mi * 16 + quad * 4;
            #pragma unroll
            for (int r = 0; r < 4; r++) {
                float v = acc[mi][nj][r] + bias;
                a1[(size_t)(gm + r) * 128 + gn] = f2bf(fmaxf(v, 0.0f));
            }
        }
}

// fc2: a1 @ wfc2 + b + residual(x2) -> out (fp32)
__global__ __launch_bounds__(256) void gemm_fc2(
    const u16* __restrict__ a1, const u16* __restrict__ wfc2T,
    const float* __restrict__ b_fc2, const u16* __restrict__ x2,
    float* __restrict__ out) {
    __shared__ u16 lds[GEMM_LDS_ELEMS];
    f32x4 acc[4][2];
    ZERO_ACC(acc)
    int m0 = blockIdx.x * 128, n0 = blockIdx.y * 64;
    gemm_tile<128>(a1, wfc2T, m0, n0, lds, acc);
    EPILOG_IDX
    #pragma unroll
    for (int mi = 0; mi < 4; mi++)
        #pragma unroll
        for (int nj = 0; nj < 2; nj++) {
            int gn = n0 + wc + nj * 16 + row;
            float bias = b_fc2[gn];
            int gm = m0 + wr + mi * 16 + quad * 4;
            #pragma unroll
            for (int r = 0; r < 4; r++) {
                size_t idx = (size_t)(gm + r) * 256 + gn;
                out[idx] = acc[mi][nj][r] + bias + bf2f(x2[idx]);
            }
        }
}

// ---------------------------------------------------------------------------
// Flash attention v4: 64 q-rows/block, 4 waves x 16 rows, no split-K.
// Grid 512 = 32 batches x 16 qtiles; CU pairs (rr, rr+8) -> (qt, 15-qt) so
// resident pairs have equal work.
// K (32x256) and V^T (256x32) bf16 tiles double-buffered in LDS, staged via
// global_load_lds (16B/lane) with inverse-XOR-swizzled GLOBAL source so the
// swizzled LDS reads are ~2-way-conflict-free (guide rule #21).
// Pipeline: issue loads for tile t+1, compute tile t, one __syncthreads
// (implicit vmcnt(0) drain) per iteration -> load latency hides under compute.
// Online softmax with defer-max (THR=8) skips most O-rescales.
// ---------------------------------------------------------------------------
__global__ __launch_bounds__(256) void attn_kernel(
    const u16* __restrict__ q, const u16* __restrict__ k,
    const u16* __restrict__ vT, u16* __restrict__ ao) {
    __shared__ u16 k_lds[2][32 * 256];   // 2 x 16 KB, K tile [s][d]
    __shared__ u16 v_lds[2][256 * 32];   // 2 x 16 KB, V^T tile [d][s]
    __shared__ u16 p_lds[4][16 * 40];    // 5 KB, wave-private P staging

    int j = blockIdx.x;
    int b = j & 31, rr = j >> 5;             // rr 0..15
    int qt = (rr < 8) ? rr : 23 - rr;        // balance: (rr, rr+8) -> (qt, 15-qt)
    int tid = threadIdx.x;
    int lane = tid & 63, wave = tid >> 6;
    int row = lane & 15, quad = lane >> 4;
    int q0 = qt * 64;
    int qrow0 = q0 + wave * 16;

    const u16* qb = q + ((size_t)b << 10) * 256;
    const u16* kb = k + ((size_t)b << 10) * 256;
    const u16* vb = vT + (((size_t)b * 256) << 10);

    const int kxor = (row & 7) << 3;   // u16-unit XOR for K reads (bytes: <<4)
    const int vxor = (row & 6) << 2;   // u16-unit XOR for V reads (bytes: <<3)

    // Q fragments held in registers for the whole kernel (pre-scaled by 1/16)
    bf16x8 qf[8];
    #pragma unroll
    for (int kf = 0; kf < 8; kf++)
        qf[kf] = *(const bf16x8*)(qb + (size_t)(qrow0 + row) * 256 + kf * 32 + quad * 8);

    f32x4 o[16];
    #pragma unroll
    for (int n = 0; n < 16; n++)
        #pragma unroll
        for (int e = 0; e < 4; e++) o[n][e] = 0.0f;
    float m_i[4], l_i[4];
    #pragma unroll
    for (int r = 0; r < 4; r++) { m_i[r] = -1e30f; l_i[r] = 0.0f; }

    int nkt = 2 * qt + 2;                // 32-wide k-tiles staged
    int wlast = 2 * qt + (wave >> 1);    // last tile this wave computes

    // stage tile kt -> buffer bf: 8 global_load_lds per wave (4 K + 4 V).
    // LDS dest is linear (wave-uniform base + lane*16); the XOR swizzle is
    // applied to the per-lane GLOBAL source column instead.
    auto stage = [&](int bf, int kt) {
        int k0 = kt << 5;
        #pragma unroll
        for (int c = 0; c < 4; c++) {
            int blk = wave * 4 + c;
            int B = (blk << 10) + lane * 16;          // byte offset in 16KB tile
            // K: 32 rows x 512 B
            int rk = B >> 9;
            int ck = (B & 511) ^ ((rk & 7) << 4);
            gload16(kb + (size_t)(k0 + rk) * 256 + (ck >> 1),
                    &k_lds[bf][blk << 9]);
            // V^T: 256 rows x 64 B
            int rv = B >> 6;
            int cv = (B & 63) ^ ((rv & 6) << 3);
            gload16(vb + ((size_t)rv << 10) + k0 + (cv >> 1),
                    &v_lds[bf][blk << 9]);
        }
    };

    stage(0, 0);
    __syncthreads();                       // vmcnt(0) drain + barrier

    for (int kt = 0; kt < nkt; kt++) {
        int cur = kt & 1;
        if (kt + 1 < nkt) stage(cur ^ 1, kt + 1);   // prefetch next tile
        if (kt <= wlast) {
            const u16* kl = k_lds[cur];
            const u16* vl = v_lds[cur];

            // S = Q K^T : 16 x 32
            f32x4 sf[2];
            #pragma unroll
            for (int jn = 0; jn < 2; jn++)
                #pragma unroll
                for (int e = 0; e < 4; e++) sf[jn][e] = 0.0f;
            __builtin_amdgcn_s_setprio(1);
            #pragma unroll
            for (int kf = 0; kf < 8; kf++)
                #pragma unroll
                for (int jn = 0; jn < 2; jn++) {
                    bf16x8 bfrag = *(const bf16x8*)(kl +
                        ((((jn * 16 + row) * 256) + kf * 32 + quad * 8) ^ kxor));
                    sf[jn] = __builtin_amdgcn_mfma_f32_16x16x32_bf16(
                        qf[kf], bfrag, sf[jn], 0, 0, 0);
                }
            __builtin_amdgcn_s_setprio(0);

            int kk0 = kt * 32;
            bool diag = (kt == wlast);     // only the last tile needs masking
            int qrow = qrow0 + quad * 4;
            float sv[2][4];
            #pragma unroll
            for (int jn = 0; jn < 2; jn++)
                #pragma unroll
                for (int r = 0; r < 4; r++) {
                    float v = sf[jn][r];
                    if (diag && (kk0 + jn * 16 + row > qrow + r)) v = MASKV;
                    sv[jn][r] = v;
                }

            // online softmax with defer-max (THR=8)
            float pmax[4];
            int need = 0;
            #pragma unroll
            for (int r = 0; r < 4; r++) {
                float t = fmaxf(sv[0][r], sv[1][r]);
                t = fmaxf(t, __shfl_xor(t, 1));
                t = fmaxf(t, __shfl_xor(t, 2));
                t = fmaxf(t, __shfl_xor(t, 4));
                t = fmaxf(t, __shfl_xor(t, 8));
                pmax[r] = t;
                need |= (t > m_i[r] + 8.0f) ? 1 : 0;
            }
            if (__any(need)) {
                #pragma unroll
                for (int r = 0; r < 4; r++) {
                    float mnew = fmaxf(m_i[r], pmax[r]);
                    float al = __expf(m_i[r] - mnew);
                    m_i[r] = mnew;
                    l_i[r] *= al;
                    #pragma unroll
                    for (int n = 0; n < 16; n++) o[n][r] *= al;
                }
            }
            #pragma unroll
            for (int r = 0; r < 4; r++) {
                float ps = 0.0f;
                #pragma unroll
                for (int jn = 0; jn < 2; jn++) {
                    sv[jn][r] = __expf(sv[jn][r] - m_i[r]);
                    ps += sv[jn][r];
                }
                ps += __shfl_xor(ps, 1);
                ps += __shfl_xor(ps, 2);
                ps += __shfl_xor(ps, 4);
                ps += __shfl_xor(ps, 8);
                l_i[r] += ps;
            }

            // P: C-layout -> wave-private LDS -> A-layout (one frag, K=32)
            u16* pw = p_lds[wave];
            #pragma unroll
            for (int jn = 0; jn < 2; jn++)
                #pragma unroll
                for (int r = 0; r < 4; r++)
                    pw[(quad * 4 + r) * 40 + jn * 16 + row] = f2bf(sv[jn][r]);
            bf16x8 pf = *(const bf16x8*)(pw + row * 40 + quad * 8);

            // O += P V
            __builtin_amdgcn_s_setprio(1);
            #pragma unroll
            for (int n = 0; n < 16; n++) {
                bf16x8 bv = *(const bf16x8*)(vl +
                    ((((n * 16 + row) * 32) + quad * 8) ^ vxor));
                o[n] = __builtin_amdgcn_mfma_f32_16x16x32_bf16(pf, bv, o[n], 0, 0, 0);
            }
            __builtin_amdgcn_s_setprio(0);
        }
        __syncthreads();   // vmcnt(0): prefetched tile landed; buffers swap
    }

    // epilogue: normalize and store
    float inv[4];
    #pragma unroll
    for (int r = 0; r < 4; r++) inv[r] = 1.0f / l_i[r];
    u16* aob = ao + (((size_t)b << 10) + qrow0) * 256;
    #pragma unroll
    for (int r = 0; r < 4; r++)
        #pragma unroll
        for (int n = 0; n < 16; n++)
            aob[(size_t)(quad * 4 + r) * 256 + n * 16 + row] =
                f2bf(o[n][r] * inv[r]);
}

// ---------------------------------------------------------------------------
extern "C" void kernel_launch(void* const* d_in, const int* in_sizes, int n_in,
                              void* d_out, int out_size, void* d_ws, size_t ws_size,
                              hipStream_t stream) {
    const float* x      = (const float*)d_in[0];
    const float* ln1_s  = (const float*)d_in[1];
    const float* ln1_b  = (const float*)d_in[2];
    const float* w_qkv  = (const float*)d_in[3];
    const float* b_qkv  = (const float*)d_in[4];
    const float* w_proj = (const float*)d_in[5];
    const float* b_proj = (const float*)d_in[6];
    const float* ln2_s  = (const float*)d_in[7];
    const float* ln2_b  = (const float*)d_in[8];
    const float* w_fc1  = (const float*)d_in[9];
    const float* b_fc1  = (const float*)d_in[10];
    const float* w_fc2  = (const float*)d_in[11];
    const float* b_fc2  = (const float*)d_in[12];
    float* out = (float*)d_out;

    // LN outputs live inside d_out (33.5 MB = 2 x 16.8 MB bf16), dead before
    // fc2 overwrites it. d_out is re-poisoned each launch; we write-then-read.
    u16* h  = (u16*)d_out;                     // LN1(x)
    u16* h2 = h + (size_t)NROWS * 256;         // LN2(x2)

    u16* W = (u16*)d_ws;
    u16* wqkvT  = W;                           // 768*256
    u16* wprojT = wqkvT + 196608;              // 256*256
    u16* wfc1T  = wprojT + 65536;              // 128*256
    u16* wfc2T  = wfc1T + 32768;               // 256*128
    u16* buf1   = wfc2T + 32768;               // q, then attn-out (in place)
    u16* buf2   = buf1 + (size_t)NROWS * 256;  // k, then x2
    u16* buf3   = buf2 + (size_t)NROWS * 256;  // vT, then a1

    transpose_weights<<<dim3(64), dim3(256), 0, stream>>>(
        w_qkv, wqkvT, w_proj, wprojT, w_fc1, wfc1T, w_fc2, wfc2T);
    ln_fused<float><<<dim3(NROWS / 4), dim3(256), 0, stream>>>(
        x, ln1_s, ln1_b, h);
    gemm_qkv<<<dim3(NROWS / 128, 12), dim3(256), 0, stream>>>(
        h, wqkvT, b_qkv, buf1, buf2, buf3);
    attn_kernel<<<dim3(512), dim3(256), 0, stream>>>(
        buf1, buf2, buf3, buf1);
    gemm_proj<<<dim3(NROWS / 128, 4), dim3(256), 0, stream>>>(
        buf1, wprojT, b_proj, x, buf2);
    ln_fused<u16><<<dim3(NROWS / 4), dim3(256), 0, stream>>>(
        buf2, ln2_s, ln2_b, h2);
    gemm_fc1<<<dim3(NROWS / 128, 2), dim3(256), 0, stream>>>(
        h2, wfc1T, b_fc1, buf3);
    gemm_fc2<<<dim3(NROWS / 128, 4), dim3(256), 0, stream>>>(
        buf3, wfc2T, b_fc2, buf2, out);
}

// Round 2
// 274.871 us; speedup vs baseline: 1.1029x; 1.0117x over previous
//
#include <hip/hip_runtime.h>
#include <hip/hip_bf16.h>

#define D_MODEL 256
#define D_HID   128
#define SEQ     1024
#define NBATCH  32
#define NROWS   (NBATCH * SEQ)    // 32768
#define MASKV   -10000.0f
#define EPSLN   1e-5f

typedef unsigned short u16;
using bf16x8 = __attribute__((ext_vector_type(8))) short;
using f32x4  = __attribute__((ext_vector_type(4))) float;

union U8 { uint4 v; u16 s[8]; };

__device__ __forceinline__ float bf2f(u16 u) {
    unsigned int x = ((unsigned int)u) << 16;
    return __uint_as_float(x);
}
__device__ __forceinline__ u16 f2bf(float f) {
    unsigned int u = __float_as_uint(f);
    u += 0x7fff + ((u >> 16) & 1);   // RNE
    return (u16)(u >> 16);
}
__device__ __forceinline__ void load4(const float* p, float* f) {
    float4 a = *(const float4*)p;
    f[0] = a.x; f[1] = a.y; f[2] = a.z; f[3] = a.w;
}
__device__ __forceinline__ void load4(const u16* p, float* f) {
    ushort4 v = *(const ushort4*)p;
    f[0] = bf2f(v.x); f[1] = bf2f(v.y); f[2] = bf2f(v.z); f[3] = bf2f(v.w);
}
// async global->LDS, 16B per lane; LDS dest = wave-uniform base + lane*16
__device__ __forceinline__ void gload16(const u16* g, u16* l) {
    __builtin_amdgcn_global_load_lds(
        (const __attribute__((address_space(1))) void*)g,
        (__attribute__((address_space(3))) void*)l, 16, 0, 0);
}

// DPP cross-lane: VALU-pipe butterfly over the 16 'row' lanes (vs ds_bpermute
// for __shfl_xor). 0xB1=quad_perm(1,0,3,2)=xor1, 0x4E=quad_perm(2,3,0,1)=xor2,
// 0x141=row_half_mirror (valid as xor4 once quads are uniform),
// 0x140=row_mirror (valid as xor8 once 8-groups are uniform).
template <int CTRL>
__device__ __forceinline__ float dpp_mov(float v) {
    return __int_as_float(__builtin_amdgcn_update_dpp(
        0, __float_as_int(v), CTRL, 0xf, 0xf, true));
}
__device__ __forceinline__ float red16_max(float v) {
    v = fmaxf(v, dpp_mov<0xB1>(v));
    v = fmaxf(v, dpp_mov<0x4E>(v));
    v = fmaxf(v, dpp_mov<0x141>(v));
    v = fmaxf(v, dpp_mov<0x140>(v));
    return v;
}
__device__ __forceinline__ float red16_sum(float v) {
    v += dpp_mov<0xB1>(v);
    v += dpp_mov<0x4E>(v);
    v += dpp_mov<0x141>(v);
    v += dpp_mov<0x140>(v);
    return v;
}

// ---------------------------------------------------------------------------
// Weight transposes: fp32 W[K][N] -> bf16 WT[N][K]
// ---------------------------------------------------------------------------
__global__ __launch_bounds__(256) void transpose_weights(
    const float* __restrict__ wqkv, u16* __restrict__ wqkvT,
    const float* __restrict__ wproj, u16* __restrict__ wprojT,
    const float* __restrict__ wfc1, u16* __restrict__ wfc1T,
    const float* __restrict__ wfc2, u16* __restrict__ wfc2T) {
    int tid = blockIdx.x * 256 + threadIdx.x;
    int stride = gridDim.x * 256;
    for (int i = tid; i < 768 * 256; i += stride) {
        int n = i >> 8, k = i & 255;
        wqkvT[i] = f2bf(wqkv[k * 768 + n]);
    }
    for (int i = tid; i < 256 * 256; i += stride) {
        int n = i >> 8, k = i & 255;
        wprojT[i] = f2bf(wproj[k * 256 + n]);
    }
    for (int i = tid; i < 128 * 256; i += stride) {
        int n = i >> 8, k = i & 255;
        wfc1T[i] = f2bf(wfc1[k * 128 + n]);
    }
    for (int i = tid; i < 256 * 128; i += stride) {
        int n = i >> 7, k = i & 127;
        wfc2T[i] = f2bf(wfc2[k * 256 + n]);
    }
}

// ---------------------------------------------------------------------------
// Fused LayerNorm: one wave per row (256 cols, 4/lane), writes bf16 row.
// ---------------------------------------------------------------------------
template <typename TX>
__global__ __launch_bounds__(256) void ln_fused(
    const TX* __restrict__ x, const float* __restrict__ gamma,
    const float* __restrict__ beta, u16* __restrict__ out) {
    int wave = threadIdx.x >> 6, lane = threadIdx.x & 63;
    int row = blockIdx.x * 4 + wave;
    float f[4];
    load4(x + (size_t)row * D_MODEL + lane * 4, f);
    float s  = f[0] + f[1] + f[2] + f[3];
    float sq = f[0] * f[0] + f[1] * f[1] + f[2] * f[2] + f[3] * f[3];
    #pragma unroll
    for (int off = 1; off < 64; off <<= 1) {
        s  += __shfl_xor(s, off);
        sq += __shfl_xor(sq, off);
    }
    float mu   = s * (1.0f / 256.0f);
    float var  = sq * (1.0f / 256.0f) - mu * mu;
    float rstd = rsqrtf(var + EPSLN);
    float g[4], be[4];
    load4(gamma + lane * 4, g);
    load4(beta + lane * 4, be);
    ushort4 o;
    o.x = f2bf((f[0] - mu) * rstd * g[0] + be[0]);
    o.y = f2bf((f[1] - mu) * rstd * g[1] + be[1]);
    o.z = f2bf((f[2] - mu) * rstd * g[2] + be[2]);
    o.w = f2bf((f[3] - mu) * rstd * g[3] + be[3]);
    *(ushort4*)(out + (size_t)row * D_MODEL + lane * 4) = o;
}

// ---------------------------------------------------------------------------
// 128x64 GEMM tile mainloop. 4 waves in 2x2; each wave 64x32 (acc[4][2]).
// ---------------------------------------------------------------------------
#define GEMM_LDS_ELEMS ((128 + 64) * 136)

template <int K>
__device__ __forceinline__ void gemm_tile(
    const u16* __restrict__ A, const u16* __restrict__ BT,
    int m0, int n0, u16* lds, f32x4 acc[4][2]) {
    constexpr int KC = 128, KP = 136;
    u16* ldsA = lds;
    u16* ldsB = lds + 128 * KP;
    const int tid = threadIdx.x;
    const int lane = tid & 63, wave = tid >> 6;
    const int wr = (wave >> 1) * 64, wc = (wave & 1) * 32;
    const int row = lane & 15, quad = lane >> 4;

    for (int ks = 0; ks < K; ks += KC) {
        __syncthreads();
        for (int i = tid; i < 2048; i += 256) {          // A: 128 x 128
            int i8 = i * 8;
            int r = i8 >> 7, c = i8 & 127;
            *(uint4*)(ldsA + r * KP + c) =
                *(const uint4*)(A + (size_t)(m0 + r) * K + ks + c);
        }
        for (int i = tid; i < 1024; i += 256) {          // B: 64 x 128
            int i8 = i * 8;
            int r = i8 >> 7, c = i8 & 127;
            *(uint4*)(ldsB + r * KP + c) =
                *(const uint4*)(BT + (size_t)(n0 + r) * K + ks + c);
        }
        __syncthreads();
        #pragma unroll
        for (int k0 = 0; k0 < KC; k0 += 32) {
            bf16x8 a[4], b[2];
            #pragma unroll
            for (int mi = 0; mi < 4; mi++)
                a[mi] = *(const bf16x8*)(ldsA + (wr + mi * 16 + row) * KP + k0 + quad * 8);
            #pragma unroll
            for (int nj = 0; nj < 2; nj++)
                b[nj] = *(const bf16x8*)(ldsB + (wc + nj * 16 + row) * KP + k0 + quad * 8);
            #pragma unroll
            for (int mi = 0; mi < 4; mi++)
                #pragma unroll
                for (int nj = 0; nj < 2; nj++)
                    acc[mi][nj] = __builtin_amdgcn_mfma_f32_16x16x32_bf16(
                        a[mi], b[nj], acc[mi][nj], 0, 0, 0);
        }
    }
}

#define ZERO_ACC(acc)                                        \
    _Pragma("unroll") for (int i_ = 0; i_ < 4; i_++)         \
    _Pragma("unroll") for (int j_ = 0; j_ < 2; j_++)         \
    _Pragma("unroll") for (int e_ = 0; e_ < 4; e_++) acc[i_][j_][e_] = 0.0f;

#define EPILOG_IDX                                           \
    int lane = threadIdx.x & 63, wave = threadIdx.x >> 6;    \
    int wr = (wave >> 1) * 64, wc = (wave & 1) * 32;         \
    int row = lane & 15, quad = lane >> 4;

// QKV: h @ wqkv + b -> q (pre-scaled 1/16), k, vT[b,256,s]
__global__ __launch_bounds__(256) void gemm_qkv(
    const u16* __restrict__ h, const u16* __restrict__ wqkvT,
    const float* __restrict__ b_qkv,
    u16* __restrict__ q, u16* __restrict__ kk, u16* __restrict__ vT) {
    __shared__ u16 lds[GEMM_LDS_ELEMS];
    f32x4 acc[4][2];
    ZERO_ACC(acc)
    int m0 = blockIdx.x * 128, n0 = blockIdx.y * 64;
    gemm_tile<256>(h, wqkvT, m0, n0, lds, acc);
    EPILOG_IDX
    #pragma unroll
    for (int mi = 0; mi < 4; mi++) {
        #pragma unroll
        for (int nj = 0; nj < 2; nj++) {
            int gn = n0 + wc + nj * 16 + row;
            float bias = b_qkv[gn];
            int gm = m0 + wr + mi * 16 + quad * 4;
            if (gn < 256) {          // q, pre-scaled by 1/sqrt(D)=1/16
                #pragma unroll
                for (int r = 0; r < 4; r++)
                    q[(size_t)(gm + r) * 256 + gn] =
                        f2bf((acc[mi][nj][r] + bias) * 0.0625f);
            } else if (gn < 512) {   // k
                int col = gn - 256;
                #pragma unroll
                for (int r = 0; r < 4; r++)
                    kk[(size_t)(gm + r) * 256 + col] = f2bf(acc[mi][nj][r] + bias);
            } else {                 // v -> vT[b][d][s]
                int d = gn - 512;
                int b = gm >> 10, s = gm & 1023;
                ushort4 pack;
                pack.x = f2bf(acc[mi][nj][0] + bias);
                pack.y = f2bf(acc[mi][nj][1] + bias);
                pack.z = f2bf(acc[mi][nj][2] + bias);
                pack.w = f2bf(acc[mi][nj][3] + bias);
                *(ushort4*)(vT + ((size_t)(b * 256 + d) << 10) + s) = pack;
            }
        }
    }
}

// proj: ao @ wproj + b + residual(x fp32) -> x2 (bf16)
__global__ __launch_bounds__(256) void gemm_proj(
    const u16* __restrict__ ao, const u16* __restrict__ wprojT,
    const float* __restrict__ b_proj, const float* __restrict__ x_in,
    u16* __restrict__ x2) {
    __shared__ u16 lds[GEMM_LDS_ELEMS];
    f32x4 acc[4][2];
    ZERO_ACC(acc)
    int m0 = blockIdx.x * 128, n0 = blockIdx.y * 64;
    gemm_tile<256>(ao, wprojT, m0, n0, lds, acc);
    EPILOG_IDX
    #pragma unroll
    for (int mi = 0; mi < 4; mi++)
        #pragma unroll
        for (int nj = 0; nj < 2; nj++) {
            int gn = n0 + wc + nj * 16 + row;
            float bias = b_proj[gn];
            int gm = m0 + wr + mi * 16 + quad * 4;
            #pragma unroll
            for (int r = 0; r < 4; r++) {
                size_t idx = (size_t)(gm + r) * 256 + gn;
                x2[idx] = f2bf(acc[mi][nj][r] + bias + x_in[idx]);
            }
        }
}

// fc1: h2 @ wfc1 + b, ReLU -> a1
__global__ __launch_bounds__(256) void gemm_fc1(
    const u16* __restrict__ h2, const u16* __restrict__ wfc1T,
    const float* __restrict__ b_fc1, u16* __restrict__ a1) {
    __shared__ u16 lds[GEMM_LDS_ELEMS];
    f32x4 acc[4][2];
    ZERO_ACC(acc)
    int m0 = blockIdx.x * 128, n0 = blockIdx.y * 64;
    gemm_tile<256>(h2, wfc1T, m0, n0, lds, acc);
    EPILOG_IDX
    #pragma unroll
    for (int mi = 0; mi < 4; mi++)
        #pragma unroll
        for (int nj = 0; nj < 2; nj++) {
            int gn = n0 + wc + nj * 16 + row;
            float bias = b_fc1[gn];
            int gm = m0 + wr + mi * 16 + quad * 4;
            #pragma unroll
            for (int r = 0; r < 4; r++) {
                float v = acc[mi][nj][r] + bias;
                a1[(size_t)(gm + r) * 128 + gn] = f2bf(fmaxf(v, 0.0f));
            }
        }
}

// fc2: a1 @ wfc2 + b + residual(x2) -> out (fp32)
__global__ __launch_bounds__(256) void gemm_fc2(
    const u16* __restrict__ a1, const u16* __restrict__ wfc2T,
    const float* __restrict__ b_fc2, const u16* __restrict__ x2,
    float* __restrict__ out) {
    __shared__ u16 lds[GEMM_LDS_ELEMS];
    f32x4 acc[4][2];
    ZERO_ACC(acc)
    int m0 = blockIdx.x * 128, n0 = blockIdx.y * 64;
    gemm_tile<128>(a1, wfc2T, m0, n0, lds, acc);
    EPILOG_IDX
    #pragma unroll
    for (int mi = 0; mi < 4; mi++)
        #pragma unroll
        for (int nj = 0; nj < 2; nj++) {
            int gn = n0 + wc + nj * 16 + row;
            float bias = b_fc2[gn];
            int gm = m0 + wr + mi * 16 + quad * 4;
            #pragma unroll
            for (int r = 0; r < 4; r++) {
                size_t idx = (size_t)(gm + r) * 256 + gn;
                out[idx] = acc[mi][nj][r] + bias + bf2f(x2[idx]);
            }
        }
}

// ---------------------------------------------------------------------------
// Flash attention v5: 64 q-rows/block, 4 waves x 16 rows.
// Work items (24 per batch, LPT-ordered longest-first for backfill):
//   qt 0..7  -> one full block each (duration 2qt+2 <= 16 k-tiles)
//   qt 8..15 -> two k-range halves [h*(qt+1), (h+1)*(qt+1)) (duration qt+1),
//              each writing UNNORMALIZED (m,l,O) partials merged by attn_merge.
// Grid 768 blocks over 512 resident slots (LDS 69KB -> 2 blocks/CU) gives real
// backfill; makespan ~17 tile-iters instead of ~34.
// DPP butterfly (VALU pipe) replaces __shfl_xor (DS pipe) in softmax reduces.
// K/V double-buffered LDS via global_load_lds w/ inverse-swizzled source.
// ---------------------------------------------------------------------------
__constant__ unsigned char WQT[24] = {7,15,15,14,14,6,13,13,12,12,5,11,
                                      11,10,10,4,9,9,8,8,3,2,1,0};
__constant__ unsigned char WH[24]  = {2,0,1,0,1,2,0,1,0,1,2,0,
                                      1,0,1,2,0,1,0,1,2,2,2,2};

__global__ __launch_bounds__(256) void attn_kernel(
    const u16* __restrict__ q, const u16* __restrict__ k,
    const u16* __restrict__ vT, u16* __restrict__ ao,
    u16* __restrict__ part, float* __restrict__ ml) {
    __shared__ u16 k_lds[2][32 * 256];   // 2 x 16 KB, K tile [s][d]
    __shared__ u16 v_lds[2][256 * 32];   // 2 x 16 KB, V^T tile [d][s]
    __shared__ u16 p_lds[4][16 * 40];    // 5 KB, wave-private P staging

    int j = blockIdx.x;
    int b = j & 31, w = j >> 5;          // w 0..23, LPT-ordered
    int qt = WQT[w], hh = WH[w];
    int lo, hi;
    if (hh == 2) { lo = 0; hi = 2 * qt + 2; }
    else         { lo = hh * (qt + 1); hi = lo + qt + 1; }

    int tid = threadIdx.x;
    int lane = tid & 63, wave = tid >> 6;
    int row = lane & 15, quad = lane >> 4;
    int q0 = qt * 64;
    int qrow0 = q0 + wave * 16;

    const u16* qb = q + ((size_t)b << 10) * 256;
    const u16* kb = k + ((size_t)b << 10) * 256;
    const u16* vb = vT + (((size_t)b * 256) << 10);

    const int kxor = (row & 7) << 3;   // u16-unit XOR for K reads
    const int vxor = (row & 6) << 2;   // u16-unit XOR for V reads

    // Q fragments held in registers for the whole kernel (pre-scaled by 1/16)
    bf16x8 qf[8];
    #pragma unroll
    for (int kf = 0; kf < 8; kf++)
        qf[kf] = *(const bf16x8*)(qb + (size_t)(qrow0 + row) * 256 + kf * 32 + quad * 8);

    f32x4 o[16];
    #pragma unroll
    for (int n = 0; n < 16; n++)
        #pragma unroll
        for (int e = 0; e < 4; e++) o[n][e] = 0.0f;
    float m_i[4], l_i[4];
    #pragma unroll
    for (int r = 0; r < 4; r++) { m_i[r] = -1e30f; l_i[r] = 0.0f; }

    int wlast = 2 * qt + (wave >> 1);    // last k-tile this wave computes

    // stage tile kt -> buffer bf: 8 global_load_lds per wave (4 K + 4 V).
    auto stage = [&](int bf, int kt) {
        int k0 = kt << 5;
        #pragma unroll
        for (int c = 0; c < 4; c++) {
            int blk = wave * 4 + c;
            int B = (blk << 10) + lane * 16;          // byte offset in 16KB tile
            // K: 32 rows x 512 B
            int rk = B >> 9;
            int ck = (B & 511) ^ ((rk & 7) << 4);
            gload16(kb + (size_t)(k0 + rk) * 256 + (ck >> 1),
                    &k_lds[bf][blk << 9]);
            // V^T: 256 rows x 64 B
            int rv = B >> 6;
            int cv = (B & 63) ^ ((rv & 6) << 3);
            gload16(vb + ((size_t)rv << 10) + k0 + (cv >> 1),
                    &v_lds[bf][blk << 9]);
        }
    };

    stage(0, lo);
    __syncthreads();                       // vmcnt(0) drain + barrier

    for (int kt = lo; kt < hi; kt++) {
        int cur = (kt - lo) & 1;
        if (kt + 1 < hi) stage(cur ^ 1, kt + 1);   // prefetch next tile
        if (kt <= wlast) {
            const u16* kl = k_lds[cur];
            const u16* vl = v_lds[cur];

            // S = Q K^T : 16 x 32
            f32x4 sf[2];
            #pragma unroll
            for (int jn = 0; jn < 2; jn++)
                #pragma unroll
                for (int e = 0; e < 4; e++) sf[jn][e] = 0.0f;
            __builtin_amdgcn_s_setprio(1);
            #pragma unroll
            for (int kf = 0; kf < 8; kf++)
                #pragma unroll
                for (int jn = 0; jn < 2; jn++) {
                    bf16x8 bfrag = *(const bf16x8*)(kl +
                        ((((jn * 16 + row) * 256) + kf * 32 + quad * 8) ^ kxor));
                    sf[jn] = __builtin_amdgcn_mfma_f32_16x16x32_bf16(
                        qf[kf], bfrag, sf[jn], 0, 0, 0);
                }
            __builtin_amdgcn_s_setprio(0);

            int kk0 = kt * 32;
            bool diag = (kt == wlast);     // only the last tile needs masking
            int qrow = qrow0 + quad * 4;
            float sv[2][4];
            #pragma unroll
            for (int jn = 0; jn < 2; jn++)
                #pragma unroll
                for (int r = 0; r < 4; r++) {
                    float v = sf[jn][r];
                    if (diag && (kk0 + jn * 16 + row > qrow + r)) v = MASKV;
                    sv[jn][r] = v;
                }

            // online softmax with defer-max (THR=8); DPP reduces (VALU pipe)
            float pmax[4];
            int need = 0;
            #pragma unroll
            for (int r = 0; r < 4; r++) {
                pmax[r] = red16_max(fmaxf(sv[0][r], sv[1][r]));
                need |= (pmax[r] > m_i[r] + 8.0f) ? 1 : 0;
            }
            if (__any(need)) {
                #pragma unroll
                for (int r = 0; r < 4; r++) {
                    float mnew = fmaxf(m_i[r], pmax[r]);
                    float al = __expf(m_i[r] - mnew);
                    m_i[r] = mnew;
                    l_i[r] *= al;
                    #pragma unroll
                    for (int n = 0; n < 16; n++) o[n][r] *= al;
                }
            }
            #pragma unroll
            for (int r = 0; r < 4; r++) {
                float ps = 0.0f;
                #pragma unroll
                for (int jn = 0; jn < 2; jn++) {
                    sv[jn][r] = __expf(sv[jn][r] - m_i[r]);
                    ps += sv[jn][r];
                }
                l_i[r] += red16_sum(ps);
            }

            // P: C-layout -> wave-private LDS -> A-layout (one frag, K=32)
            u16* pw = p_lds[wave];
            #pragma unroll
            for (int jn = 0; jn < 2; jn++)
                #pragma unroll
                for (int r = 0; r < 4; r++)
                    pw[(quad * 4 + r) * 40 + jn * 16 + row] = f2bf(sv[jn][r]);
            bf16x8 pf = *(const bf16x8*)(pw + row * 40 + quad * 8);

            // O += P V
            __builtin_amdgcn_s_setprio(1);
            #pragma unroll
            for (int n = 0; n < 16; n++) {
                bf16x8 bv = *(const bf16x8*)(vl +
                    ((((n * 16 + row) * 32) + quad * 8) ^ vxor));
                o[n] = __builtin_amdgcn_mfma_f32_16x16x32_bf16(pf, bv, o[n], 0, 0, 0);
            }
            __builtin_amdgcn_s_setprio(0);
        }
        __syncthreads();   // vmcnt(0): prefetched tile landed; buffers swap
    }

    if (hh == 2) {
        // full block: normalize and store final bf16
        float inv[4];
        #pragma unroll
        for (int r = 0; r < 4; r++) inv[r] = 1.0f / l_i[r];
        u16* aob = ao + (((size_t)b << 10) + qrow0) * 256;
        #pragma unroll
        for (int r = 0; r < 4; r++)
            #pragma unroll
            for (int n = 0; n < 16; n++)
                aob[(size_t)(quad * 4 + r) * 256 + n * 16 + row] =
                    f2bf(o[n][r] * inv[r]);
    } else {
        // split half: write unnormalized O (bf16) + per-row (m,l)
        int p = (((b << 3) | (qt - 8)) << 1) | hh;
        u16* pb = part + (((size_t)p) << 6) * 256;
        #pragma unroll
        for (int r = 0; r < 4; r++) {
            int rt = wave * 16 + quad * 4 + r;
            #pragma unroll
            for (int n = 0; n < 16; n++)
                pb[(size_t)rt * 256 + n * 16 + row] = f2bf(o[n][r]);
        }
        if (row == 0) {
            #pragma unroll
            for (int r = 0; r < 4; r++) {
                int rt = wave * 16 + quad * 4 + r;
                float2 v2; v2.x = m_i[r]; v2.y = l_i[r];
                *(float2*)(ml + ((size_t)((p << 6) + rt)) * 2) = v2;
            }
        }
    }
}

// Merge the two k-range halves for qt 8..15: standard (m,l,O) combine.
__global__ __launch_bounds__(256) void attn_merge(
    const u16* __restrict__ part, const float* __restrict__ ml,
    u16* __restrict__ ao) {
    int j = blockIdx.x;                  // 0..255 : b*8 + (qt-8)
    int b = j >> 3, qi = j & 7;
    int t = threadIdx.x;
    int r = t >> 2, cq = t & 3;          // row 0..63, col-quarter 0..3
    int pA = j << 1, pB = pA | 1;
    const float* mlA = ml + ((size_t)(pA << 6) + r) * 2;
    const float* mlB = ml + ((size_t)(pB << 6) + r) * 2;
    float mA = mlA[0], lA = mlA[1];
    float mB = mlB[0], lB = mlB[1];
    float m  = fmaxf(mA, mB);
    float eA = __expf(mA - m), eB = __expf(mB - m);
    float inv = 1.0f / (lA * eA + lB * eB);
    float sA = eA * inv, sB = eB * inv;
    const u16* oA = part + (((size_t)(pA << 6) + r) * 256) + cq * 64;
    const u16* oB = part + (((size_t)(pB << 6) + r) * 256) + cq * 64;
    u16* dst = ao + ((size_t)((b << 10) + 512 + (qi << 6) + r)) * 256 + cq * 64;
    #pragma unroll
    for (int u = 0; u < 8; u++) {
        U8 a, bb, o;
        a.v  = *(const uint4*)(oA + u * 8);
        bb.v = *(const uint4*)(oB + u * 8);
        #pragma unroll
        for (int e = 0; e < 8; e++)
            o.s[e] = f2bf(bf2f(a.s[e]) * sA + bf2f(bb.s[e]) * sB);
        *(uint4*)(dst + u * 8) = o.v;
    }
}

// ---------------------------------------------------------------------------
extern "C" void kernel_launch(void* const* d_in, const int* in_sizes, int n_in,
                              void* d_out, int out_size, void* d_ws, size_t ws_size,
                              hipStream_t stream) {
    const float* x      = (const float*)d_in[0];
    const float* ln1_s  = (const float*)d_in[1];
    const float* ln1_b  = (const float*)d_in[2];
    const float* w_qkv  = (const float*)d_in[3];
    const float* b_qkv  = (const float*)d_in[4];
    const float* w_proj = (const float*)d_in[5];
    const float* b_proj = (const float*)d_in[6];
    const float* ln2_s  = (const float*)d_in[7];
    const float* ln2_b  = (const float*)d_in[8];
    const float* w_fc1  = (const float*)d_in[9];
    const float* b_fc1  = (const float*)d_in[10];
    const float* w_fc2  = (const float*)d_in[11];
    const float* b_fc2  = (const float*)d_in[12];
    float* out = (float*)d_out;

    // d_out reuse: h (LN1 out) dies after gemm_qkv -> its 16.78MB region is
    // reused for attn split partials (exactly 512*64*256 bf16). The m,l array
    // (256KB) lives at the start of the h2 region, dead until ln2 runs (after
    // attn_merge has consumed it). fc2 overwrites d_out last.
    u16* h  = (u16*)d_out;                     // LN1(x), then attn partial O
    u16* h2 = h + (size_t)NROWS * 256;         // attn (m,l), then LN2(x2)

    u16* W = (u16*)d_ws;
    u16* wqkvT  = W;                           // 768*256
    u16* wprojT = wqkvT + 196608;              // 256*256
    u16* wfc1T  = wprojT + 65536;              // 128*256
    u16* wfc2T  = wfc1T + 32768;               // 256*128
    u16* buf1   = wfc2T + 32768;               // q, then attn-out (in place)
    u16* buf2   = buf1 + (size_t)NROWS * 256;  // k, then x2
    u16* buf3   = buf2 + (size_t)NROWS * 256;  // vT, then a1

    u16*   part  = h;                          // attn partial O (bf16)
    float* mlbuf = (float*)h2;                 // attn partial (m,l)

    transpose_weights<<<dim3(64), dim3(256), 0, stream>>>(
        w_qkv, wqkvT, w_proj, wprojT, w_fc1, wfc1T, w_fc2, wfc2T);
    ln_fused<float><<<dim3(NROWS / 4), dim3(256), 0, stream>>>(
        x, ln1_s, ln1_b, h);
    gemm_qkv<<<dim3(NROWS / 128, 12), dim3(256), 0, stream>>>(
        h, wqkvT, b_qkv, buf1, buf2, buf3);
    attn_kernel<<<dim3(768), dim3(256), 0, stream>>>(
        buf1, buf2, buf3, buf1, part, mlbuf);
    attn_merge<<<dim3(256), dim3(256), 0, stream>>>(
        part, mlbuf, buf1);
    gemm_proj<<<dim3(NROWS / 128, 4), dim3(256), 0, stream>>>(
        buf1, wprojT, b_proj, x, buf2);
    ln_fused<u16><<<dim3(NROWS / 4), dim3(256), 0, stream>>>(
        buf2, ln2_s, ln2_b, h2);
    gemm_fc1<<<dim3(NROWS / 128, 2), dim3(256), 0, stream>>>(
        h2, wfc1T, b_fc1, buf3);
    gemm_fc2<<<dim3(NROWS / 128, 4), dim3(256), 0, stream>>>(
        buf3, wfc2T, b_fc2, buf2, out);
}